// Round 4
// baseline (94.857 us; speedup 1.0000x reference)
//
#include <hip/hip_runtime.h>

#define H 1024
#define W 1024
#define L 8
#define QH 1025
#define QW 1025
#define OUT0 192
#define QUANT_ELEMS (L * QH * QW)

#define CROWS 32              // rows per chunk
#define NCHUNK 32
#define BPC 72                // units per chunk: 64 co planes + 8 quant planes
#define NUNITS (NCHUNK * BPC) // 2304
#define UPB 3                 // units per block
#define GRID_MAIN (NUNITS / UPB)  // 768 = exactly 3 blocks per CU

// ws float slots (all written unconditionally every call -> no init kernel):
// [0..255] per-block min partials, [256..511] max partials,
// [512..512+2047] sta partials indexed c*64+k
#define WS_MINP 0
#define WS_MAXP 256
#define WS_STA  512

typedef float f32x4 __attribute__((ext_vector_type(4)));

__device__ __forceinline__ void nt_store4(float* p, float a, float b, float c, float d) {
    f32x4 v = {a, b, c, d};
    __builtin_nontemporal_store(v, (f32x4*)p);
}
__device__ __forceinline__ float qlev(float mn, float step, float mx, int i) {
    return (i == L - 1) ? mx : mn + step * (float)i;
}

__global__ __launch_bounds__(256) void k_minmax(const float4* __restrict__ x4,
                                                float* __restrict__ ws) {
    const int t = threadIdx.x, b = blockIdx.x;
    float mn = 1e30f, mx = -1e30f;
    #pragma unroll
    for (int i = 0; i < 4; ++i) {
        float4 v = x4[b * 1024 + i * 256 + t];
        mn = fminf(mn, fminf(fminf(v.x, v.y), fminf(v.z, v.w)));
        mx = fmaxf(mx, fmaxf(fmaxf(v.x, v.y), fmaxf(v.z, v.w)));
    }
    #pragma unroll
    for (int m = 1; m < 64; m <<= 1) {
        mn = fminf(mn, __shfl_xor(mn, m, 64));
        mx = fmaxf(mx, __shfl_xor(mx, m, 64));
    }
    __shared__ float smn[4], smx[4];
    if ((t & 63) == 0) { smn[t >> 6] = mn; smx[t >> 6] = mx; }
    __syncthreads();
    if (t == 0) {
        ws[WS_MINP + b] = fminf(fminf(smn[0], smn[1]), fminf(smn[2], smn[3]));
        ws[WS_MAXP + b] = fmaxf(fmaxf(smx[0], smx[1]), fmaxf(smx[2], smx[3]));
    }
}

// Balanced plane-major: 768 blocks (3/CU), 3 units each, all co-resident,
// uniform bytes per block -> no tail. Unit u: chunk c=u/72, plane k=u%72.
__global__ __launch_bounds__(256) void k_main(const float* __restrict__ x,
                                              float* __restrict__ out,
                                              float* __restrict__ ws) {
    const int t = threadIdx.x;
    __shared__ float smn[4], smx[4], red[4];

    // reduce the 256 min/max partials (L2-broadcast, ~300 cycles)
    float mn = ws[WS_MINP + t], mx = ws[WS_MAXP + t];
    #pragma unroll
    for (int m = 1; m < 64; m <<= 1) {
        mn = fminf(mn, __shfl_xor(mn, m, 64));
        mx = fmaxf(mx, __shfl_xor(mx, m, 64));
    }
    if ((t & 63) == 0) { smn[t >> 6] = mn; smx[t >> 6] = mx; }
    __syncthreads();
    const float mnv = fminf(fminf(smn[0], smn[1]), fminf(smn[2], smn[3]));
    const float mxv = fmaxf(fmaxf(smx[0], smx[1]), fmaxf(smx[2], smx[3]));
    const float step = (mxv - mnv) * (1.0f / 7.0f);

    float* __restrict__ quant = out + OUT0;
    float* __restrict__ co    = out + OUT0 + QUANT_ELEMS;
    const int w0 = t * 4;
    const bool ok3 = (w0 + 4 < W);   // lane 255's 4th shifted col is the pad

    #pragma unroll
    for (int uu = 0; uu < UPB; ++uu) {
        const int u = blockIdx.x * UPB + uu;
        const int c = u / BPC, k = u - c * BPC;
        const int r0 = c * CROWS;

        if (k < 64) {
            const float qi = qlev(mnv, step, mxv, k >> 3);
            const float qj = qlev(mnv, step, mxv, k & 7);
            float* cop = co + k * (H * W) + r0 * W + w0;
            float4 cur = *(const float4*)(x + r0 * W + w0);
            float acc = 0.0f;

            for (int r = 0; r < CROWS; ++r) {
                const int h = r0 + r;
                const bool hok = (h + 1 < H);
                float4 nxt = make_float4(0.f, 0.f, 0.f, 0.f);
                float e = 0.f;
                if (hok) {
                    nxt = *(const float4*)(x + (h + 1) * W + w0);
                    if (ok3) e = x[(h + 1) * W + w0 + 4];
                }
                float d;
                d = cur.x - qi; float l0 = __expf(-16.f * d * d);
                d = cur.y - qi; float l1 = __expf(-16.f * d * d);
                d = cur.z - qi; float l2 = __expf(-16.f * d * d);
                d = cur.w - qi; float l3 = __expf(-16.f * d * d);
                d = nxt.y - qj; float p0 = hok ? __expf(-16.f * d * d) : 0.f;
                d = nxt.z - qj; float p1 = hok ? __expf(-16.f * d * d) : 0.f;
                d = nxt.w - qj; float p2 = hok ? __expf(-16.f * d * d) : 0.f;
                d = e     - qj; float p3 = (hok && ok3) ? __expf(-16.f * d * d) : 0.f;

                float v0 = l0 * p0, v1 = l1 * p1, v2 = l2 * p2, v3 = l3 * p3;
                nt_store4(cop, v0, v1, v2, v3);
                cop += W;
                acc += (v0 + v1) + (v2 + v3);
                cur = nxt;
            }

            #pragma unroll
            for (int m = 1; m < 64; m <<= 1) acc += __shfl_xor(acc, m, 64);
            __syncthreads();                       // red[] reuse across units
            if ((t & 63) == 0) red[t >> 6] = acc;
            __syncthreads();
            if (t == 0)
                ws[WS_STA + c * 64 + k] = (red[0] + red[1]) + (red[2] + red[3]);
        } else {
            const int i = k - 64;
            const float qi = qlev(mnv, step, mxv, i);
            for (int r = 0; r < CROWS; ++r) {
                const int h = r0 + r;
                float4 xl = *(const float4*)(x + h * W + w0);
                float d;
                d = xl.x - qi; float l0 = __expf(-16.f * d * d);
                d = xl.y - qi; float l1 = __expf(-16.f * d * d);
                d = xl.z - qi; float l2 = __expf(-16.f * d * d);
                d = xl.w - qi; float l3 = __expf(-16.f * d * d);
                float* row = quant + (i * QH + h) * QW + w0;
                nt_store4(row, l0, l1, l2, l3);
                if (t == 255) __builtin_nontemporal_store(0.f, row + 4); // right pad
            }
            if (c == NCHUNK - 1) {                 // bottom pad row h==1024
                for (int w = t; w < QW; w += 256)
                    __builtin_nontemporal_store(0.f, &quant[(i * QH + H) * QW + w]);
            }
        }
    }
}

__global__ void k_final(float* __restrict__ out, const float* __restrict__ ws) {
    const int t = threadIdx.x;  // 64 threads
    float mn = 1e30f, mx = -1e30f;
    #pragma unroll
    for (int i = 0; i < 4; ++i) {
        mn = fminf(mn, ws[WS_MINP + i * 64 + t]);
        mx = fmaxf(mx, ws[WS_MAXP + i * 64 + t]);
    }
    #pragma unroll
    for (int m = 1; m < 64; m <<= 1) {
        mn = fminf(mn, __shfl_xor(mn, m, 64));
        mx = fmaxf(mx, __shfl_xor(mx, m, 64));
    }
    const float step = (mx - mn) * (1.0f / 7.0f);

    float s = 0.f;
    #pragma unroll 8
    for (int c = 0; c < NCHUNK; ++c) s += ws[WS_STA + c * 64 + t];
    float tot = s;
    #pragma unroll
    for (int m = 1; m < 64; m <<= 1) tot += __shfl_xor(tot, m, 64);

    out[t]       = qlev(mn, step, mx, t & 7);   // q_h[i][j] = q_levels[j]
    out[64 + t]  = qlev(mn, step, mx, t >> 3);  // q_w[i][j] = q_levels[i]
    out[128 + t] = s / tot;                     // normalized sta
}

extern "C" void kernel_launch(void* const* d_in, const int* in_sizes, int n_in,
                              void* d_out, int out_size, void* d_ws, size_t ws_size,
                              hipStream_t stream) {
    const float* x = (const float*)d_in[0];
    float* out = (float*)d_out;
    float* ws = (float*)d_ws;

    k_minmax<<<dim3(256), dim3(256), 0, stream>>>((const float4*)x, ws);
    k_main<<<dim3(GRID_MAIN), dim3(256), 0, stream>>>(x, out, ws);
    k_final<<<dim3(1), dim3(64), 0, stream>>>(out, ws);
}

// Round 5
// 68.833 us; speedup vs baseline: 1.3781x; 1.3781x over previous
//
#include <hip/hip_runtime.h>

#define H 1024
#define W 1024
#define L 8
#define QH 1025
#define QW 1025
#define OUT0 192
#define QUANT_ELEMS (L * QH * QW)

#define CROWS 32              // rows per chunk
#define NCHUNK 32
#define BPC 72                // blocks per chunk: 64 co planes + 8 quant planes

// ws float slots (every slot below is written unconditionally every call ->
// no init kernel, no atomics, deterministic under graph replay):
// [0..255]   per-block min partials (k_minmax)
// [256..511] per-block max partials (k_minmax)
// [512..2559] sta partials, slot c*64+k written only by block (c,k)
#define WS_MINP 0
#define WS_MAXP 256
#define WS_STA  512

__device__ __forceinline__ float qlev(float mn, float step, float mx, int i) {
    return (i == L - 1) ? mx : mn + step * (float)i;
}

__global__ __launch_bounds__(256) void k_minmax(const float4* __restrict__ x4,
                                                float* __restrict__ ws) {
    const int t = threadIdx.x, b = blockIdx.x;
    float mn = 1e30f, mx = -1e30f;
    #pragma unroll
    for (int i = 0; i < 4; ++i) {
        float4 v = x4[b * 1024 + i * 256 + t];
        mn = fminf(mn, fminf(fminf(v.x, v.y), fminf(v.z, v.w)));
        mx = fmaxf(mx, fmaxf(fmaxf(v.x, v.y), fmaxf(v.z, v.w)));
    }
    #pragma unroll
    for (int m = 1; m < 64; m <<= 1) {
        mn = fminf(mn, __shfl_xor(mn, m, 64));
        mx = fmaxf(mx, __shfl_xor(mx, m, 64));
    }
    __shared__ float smn[4], smx[4];
    if ((t & 63) == 0) { smn[t >> 6] = mn; smx[t >> 6] = mx; }
    __syncthreads();
    if (t == 0) {
        ws[WS_MINP + b] = fminf(fminf(smn[0], smn[1]), fminf(smn[2], smn[3]));
        ws[WS_MAXP + b] = fmaxf(fmaxf(smx[0], smx[1]), fmaxf(smx[2], smx[3]));
    }
}

// Plane-major, one unit per block (R3 structure, regular stores).
// bid -> chunk c = bid/72 (shares x rows -> L2 reuse), plane k = bid%72.
// k < 64: co plane (i=k>>3, j=k&7), rows [c*32, c*32+32) = 128KB contiguous.
// k >= 64: quant plane i=k-64, same rows (+ pad writes).
__global__ __launch_bounds__(256) void k_main(const float* __restrict__ x,
                                              float* __restrict__ out,
                                              float* __restrict__ ws) {
    const int t = threadIdx.x;
    __shared__ float smn[4], smx[4], red[4];

    // prologue: reduce the 256 min/max partials (L2-resident, ~overlapped)
    float mn = ws[WS_MINP + t], mx = ws[WS_MAXP + t];
    #pragma unroll
    for (int m = 1; m < 64; m <<= 1) {
        mn = fminf(mn, __shfl_xor(mn, m, 64));
        mx = fmaxf(mx, __shfl_xor(mx, m, 64));
    }
    if ((t & 63) == 0) { smn[t >> 6] = mn; smx[t >> 6] = mx; }
    __syncthreads();
    const float mnv = fminf(fminf(smn[0], smn[1]), fminf(smn[2], smn[3]));
    const float mxv = fmaxf(fmaxf(smx[0], smx[1]), fmaxf(smx[2], smx[3]));
    const float step = (mxv - mnv) * (1.0f / 7.0f);

    float* __restrict__ quant = out + OUT0;
    float* __restrict__ co    = out + OUT0 + QUANT_ELEMS;

    const int bid = blockIdx.x;
    const int c = bid / BPC, k = bid - c * BPC;
    const int r0 = c * CROWS;
    const int w0 = t * 4;
    const bool ok3 = (w0 + 4 < W);   // lane 255's 4th shifted col is the pad

    if (k < 64) {
        const float qi = qlev(mnv, step, mxv, k >> 3);
        const float qj = qlev(mnv, step, mxv, k & 7);
        float* cop = co + k * (H * W) + r0 * W + w0;
        float4 cur = *(const float4*)(x + r0 * W + w0);
        float acc = 0.0f;

        for (int r = 0; r < CROWS; ++r) {
            const int h = r0 + r;
            const bool hok = (h + 1 < H);
            float4 nxt = make_float4(0.f, 0.f, 0.f, 0.f);
            float e = 0.f;
            if (hok) {
                nxt = *(const float4*)(x + (h + 1) * W + w0);
                if (ok3) e = x[(h + 1) * W + w0 + 4];
            }
            float d;
            d = cur.x - qi; float l0 = __expf(-16.f * d * d);
            d = cur.y - qi; float l1 = __expf(-16.f * d * d);
            d = cur.z - qi; float l2 = __expf(-16.f * d * d);
            d = cur.w - qi; float l3 = __expf(-16.f * d * d);
            d = nxt.y - qj; float p0 = hok ? __expf(-16.f * d * d) : 0.f;
            d = nxt.z - qj; float p1 = hok ? __expf(-16.f * d * d) : 0.f;
            d = nxt.w - qj; float p2 = hok ? __expf(-16.f * d * d) : 0.f;
            d = e     - qj; float p3 = (hok && ok3) ? __expf(-16.f * d * d) : 0.f;

            float v0 = l0 * p0, v1 = l1 * p1, v2 = l2 * p2, v3 = l3 * p3;
            *(float4*)cop = make_float4(v0, v1, v2, v3);
            cop += W;
            acc += (v0 + v1) + (v2 + v3);
            cur = nxt;
        }

        // block reduce -> exclusive slot write (no atomic, no init needed)
        #pragma unroll
        for (int m = 1; m < 64; m <<= 1) acc += __shfl_xor(acc, m, 64);
        if ((t & 63) == 0) red[t >> 6] = acc;
        __syncthreads();
        if (t == 0)
            ws[WS_STA + c * 64 + k] = (red[0] + red[1]) + (red[2] + red[3]);
    } else {
        const int i = k - 64;
        const float qi = qlev(mnv, step, mxv, i);
        for (int r = 0; r < CROWS; ++r) {
            const int h = r0 + r;
            float4 xl = *(const float4*)(x + h * W + w0);
            float d;
            d = xl.x - qi; float l0 = __expf(-16.f * d * d);
            d = xl.y - qi; float l1 = __expf(-16.f * d * d);
            d = xl.z - qi; float l2 = __expf(-16.f * d * d);
            d = xl.w - qi; float l3 = __expf(-16.f * d * d);
            float* row = quant + (i * QH + h) * QW + w0;
            *(float4*)row = make_float4(l0, l1, l2, l3);
            if (t == 255) row[4] = 0.0f;           // right pad col (w0+4 == 1024)
        }
        if (c == NCHUNK - 1) {                     // bottom pad row h==1024
            for (int w = t; w < QW; w += 256)
                quant[(i * QH + H) * QW + w] = 0.0f;
        }
    }
}

__global__ void k_final(float* __restrict__ out, const float* __restrict__ ws) {
    const int t = threadIdx.x;  // 64 threads
    float mn = 1e30f, mx = -1e30f;
    #pragma unroll
    for (int i = 0; i < 4; ++i) {
        mn = fminf(mn, ws[WS_MINP + i * 64 + t]);
        mx = fmaxf(mx, ws[WS_MAXP + i * 64 + t]);
    }
    #pragma unroll
    for (int m = 1; m < 64; m <<= 1) {
        mn = fminf(mn, __shfl_xor(mn, m, 64));
        mx = fmaxf(mx, __shfl_xor(mx, m, 64));
    }
    const float step = (mx - mn) * (1.0f / 7.0f);

    float s = 0.f;
    #pragma unroll 8
    for (int c = 0; c < NCHUNK; ++c) s += ws[WS_STA + c * 64 + t];
    float tot = s;
    #pragma unroll
    for (int m = 1; m < 64; m <<= 1) tot += __shfl_xor(tot, m, 64);

    out[t]       = qlev(mn, step, mx, t & 7);   // q_h[i][j] = q_levels[j]
    out[64 + t]  = qlev(mn, step, mx, t >> 3);  // q_w[i][j] = q_levels[i]
    out[128 + t] = s / tot;                     // normalized sta
}

extern "C" void kernel_launch(void* const* d_in, const int* in_sizes, int n_in,
                              void* d_out, int out_size, void* d_ws, size_t ws_size,
                              hipStream_t stream) {
    const float* x = (const float*)d_in[0];
    float* out = (float*)d_out;
    float* ws = (float*)d_ws;

    k_minmax<<<dim3(256), dim3(256), 0, stream>>>((const float4*)x, ws);
    k_main<<<dim3(NCHUNK * BPC), dim3(256), 0, stream>>>(x, out, ws);
    k_final<<<dim3(1), dim3(64), 0, stream>>>(out, ws);
}

// Round 6
// 65.717 us; speedup vs baseline: 1.4434x; 1.0474x over previous
//
#include <hip/hip_runtime.h>

#define H 1024
#define W 1024
#define L 8
#define QH 1025
#define QW 1025
#define OUT0 192
#define QUANT_ELEMS (L * QH * QW)

#define CROWS 32              // rows per chunk
#define NCHUNK 32
#define BPC 72                // units per chunk: 64 co planes + 8 quant planes
#define NUNITS (NCHUNK * BPC) // 2304
#define UPB 3                 // units per block (consecutive -> same chunk)
#define GRID_MAIN (NUNITS / UPB)  // 768 = exactly 3 blocks/CU, zero tail

// ws float slots (every slot written unconditionally every call -> no init
// kernel, no atomics, deterministic under graph replay):
// [0..255] min partials, [256..511] max partials, [512..2559] sta partials (c*64+k)
#define WS_MINP 0
#define WS_MAXP 256
#define WS_STA  512

__device__ __forceinline__ float qlev(float mn, float step, float mx, int i) {
    return (i == L - 1) ? mx : mn + step * (float)i;
}

__global__ __launch_bounds__(256) void k_minmax(const float4* __restrict__ x4,
                                                float* __restrict__ ws) {
    const int t = threadIdx.x, b = blockIdx.x;
    float mn = 1e30f, mx = -1e30f;
    #pragma unroll
    for (int i = 0; i < 4; ++i) {
        float4 v = x4[b * 1024 + i * 256 + t];
        mn = fminf(mn, fminf(fminf(v.x, v.y), fminf(v.z, v.w)));
        mx = fmaxf(mx, fmaxf(fmaxf(v.x, v.y), fmaxf(v.z, v.w)));
    }
    #pragma unroll
    for (int m = 1; m < 64; m <<= 1) {
        mn = fminf(mn, __shfl_xor(mn, m, 64));
        mx = fmaxf(mx, __shfl_xor(mx, m, 64));
    }
    __shared__ float smn[4], smx[4];
    if ((t & 63) == 0) { smn[t >> 6] = mn; smx[t >> 6] = mx; }
    __syncthreads();
    if (t == 0) {
        ws[WS_MINP + b] = fminf(fminf(smn[0], smn[1]), fminf(smn[2], smn[3]));
        ws[WS_MAXP + b] = fmaxf(fmaxf(smx[0], smx[1]), fmaxf(smx[2], smx[3]));
    }
}

// Balanced plane-major: 768 blocks (3/CU co-resident, no tail), 3 consecutive
// units each (same chunk). XCD swizzle: block bid runs on XCD bid%8 (dispatch
// round-robin); sbid=(bid&7)*96+(bid>>3) gives each XCD 4 whole chunks, so
// each chunk's x rows are fetched into exactly ONE L2 (perf-only heuristic).
__global__ __launch_bounds__(256) void k_main(const float* __restrict__ x,
                                              float* __restrict__ out,
                                              float* __restrict__ ws) {
    const int t = threadIdx.x;
    __shared__ float smn[4], smx[4], red[4];

    // prologue: reduce the 256 min/max partials (L2-resident)
    float mn = ws[WS_MINP + t], mx = ws[WS_MAXP + t];
    #pragma unroll
    for (int m = 1; m < 64; m <<= 1) {
        mn = fminf(mn, __shfl_xor(mn, m, 64));
        mx = fmaxf(mx, __shfl_xor(mx, m, 64));
    }
    if ((t & 63) == 0) { smn[t >> 6] = mn; smx[t >> 6] = mx; }
    __syncthreads();
    const float mnv = fminf(fminf(smn[0], smn[1]), fminf(smn[2], smn[3]));
    const float mxv = fmaxf(fmaxf(smx[0], smx[1]), fmaxf(smx[2], smx[3]));
    const float step = (mxv - mnv) * (1.0f / 7.0f);

    float* __restrict__ quant = out + OUT0;
    float* __restrict__ co    = out + OUT0 + QUANT_ELEMS;

    const int sbid = (blockIdx.x & 7) * (GRID_MAIN / 8) + (blockIdx.x >> 3);
    const int w0 = t * 4;
    const bool ok3 = (w0 + 4 < W);   // lane 255's 4th shifted col is the pad

    #pragma unroll
    for (int uu = 0; uu < UPB; ++uu) {
        const int u = sbid * UPB + uu;
        const int c = u / BPC, k = u - c * BPC;
        const int r0 = c * CROWS;

        if (k < 64) {
            const float qi = qlev(mnv, step, mxv, k >> 3);
            const float qj = qlev(mnv, step, mxv, k & 7);
            float* cop = co + k * (H * W) + r0 * W + w0;
            float4 cur = *(const float4*)(x + r0 * W + w0);
            float acc = 0.0f;

            for (int r = 0; r < CROWS; ++r) {
                const int h = r0 + r;
                const bool hok = (h + 1 < H);
                float4 nxt = make_float4(0.f, 0.f, 0.f, 0.f);
                float e = 0.f;
                if (hok) {
                    nxt = *(const float4*)(x + (h + 1) * W + w0);
                    if (ok3) e = x[(h + 1) * W + w0 + 4];
                }
                float d;
                d = cur.x - qi; float l0 = __expf(-16.f * d * d);
                d = cur.y - qi; float l1 = __expf(-16.f * d * d);
                d = cur.z - qi; float l2 = __expf(-16.f * d * d);
                d = cur.w - qi; float l3 = __expf(-16.f * d * d);
                d = nxt.y - qj; float p0 = hok ? __expf(-16.f * d * d) : 0.f;
                d = nxt.z - qj; float p1 = hok ? __expf(-16.f * d * d) : 0.f;
                d = nxt.w - qj; float p2 = hok ? __expf(-16.f * d * d) : 0.f;
                d = e     - qj; float p3 = (hok && ok3) ? __expf(-16.f * d * d) : 0.f;

                float v0 = l0 * p0, v1 = l1 * p1, v2 = l2 * p2, v3 = l3 * p3;
                *(float4*)cop = make_float4(v0, v1, v2, v3);
                cop += W;
                acc += (v0 + v1) + (v2 + v3);
                cur = nxt;
            }

            // block reduce -> exclusive slot (no atomic); syncs guard red[] reuse
            #pragma unroll
            for (int m = 1; m < 64; m <<= 1) acc += __shfl_xor(acc, m, 64);
            __syncthreads();
            if ((t & 63) == 0) red[t >> 6] = acc;
            __syncthreads();
            if (t == 0)
                ws[WS_STA + c * 64 + k] = (red[0] + red[1]) + (red[2] + red[3]);
        } else {
            const int i = k - 64;
            const float qi = qlev(mnv, step, mxv, i);
            for (int r = 0; r < CROWS; ++r) {
                const int h = r0 + r;
                float4 xl = *(const float4*)(x + h * W + w0);
                float d;
                d = xl.x - qi; float l0 = __expf(-16.f * d * d);
                d = xl.y - qi; float l1 = __expf(-16.f * d * d);
                d = xl.z - qi; float l2 = __expf(-16.f * d * d);
                d = xl.w - qi; float l3 = __expf(-16.f * d * d);
                float* row = quant + (i * QH + h) * QW + w0;
                *(float4*)row = make_float4(l0, l1, l2, l3);
                if (t == 255) row[4] = 0.0f;       // right pad col (w0+4 == 1024)
            }
            if (c == NCHUNK - 1) {                 // bottom pad row h==1024
                for (int w = t; w < QW; w += 256)
                    quant[(i * QH + H) * QW + w] = 0.0f;
            }
        }
    }
}

__global__ void k_final(float* __restrict__ out, const float* __restrict__ ws) {
    const int t = threadIdx.x;  // 64 threads
    float mn = 1e30f, mx = -1e30f;
    #pragma unroll
    for (int i = 0; i < 4; ++i) {
        mn = fminf(mn, ws[WS_MINP + i * 64 + t]);
        mx = fmaxf(mx, ws[WS_MAXP + i * 64 + t]);
    }
    #pragma unroll
    for (int m = 1; m < 64; m <<= 1) {
        mn = fminf(mn, __shfl_xor(mn, m, 64));
        mx = fmaxf(mx, __shfl_xor(mx, m, 64));
    }
    const float step = (mx - mn) * (1.0f / 7.0f);

    float s = 0.f;
    #pragma unroll 8
    for (int c = 0; c < NCHUNK; ++c) s += ws[WS_STA + c * 64 + t];
    float tot = s;
    #pragma unroll
    for (int m = 1; m < 64; m <<= 1) tot += __shfl_xor(tot, m, 64);

    out[t]       = qlev(mn, step, mx, t & 7);   // q_h[i][j] = q_levels[j]
    out[64 + t]  = qlev(mn, step, mx, t >> 3);  // q_w[i][j] = q_levels[i]
    out[128 + t] = s / tot;                     // normalized sta
}

extern "C" void kernel_launch(void* const* d_in, const int* in_sizes, int n_in,
                              void* d_out, int out_size, void* d_ws, size_t ws_size,
                              hipStream_t stream) {
    const float* x = (const float*)d_in[0];
    float* out = (float*)d_out;
    float* ws = (float*)d_ws;

    k_minmax<<<dim3(256), dim3(256), 0, stream>>>((const float4*)x, ws);
    k_main<<<dim3(GRID_MAIN), dim3(256), 0, stream>>>(x, out, ws);
    k_final<<<dim3(1), dim3(64), 0, stream>>>(out, ws);
}

// Round 7
// 64.699 us; speedup vs baseline: 1.4661x; 1.0157x over previous
//
#include <hip/hip_runtime.h>

#define H 1024
#define W 1024
#define L 8
#define QH 1025
#define QW 1025
#define OUT0 192
#define QUANT_ELEMS (L * QH * QW)

#define UROWS 16              // rows per unit
#define NUNITS 512            // 32 chunks x 8 i-groups x 2 halves = 2 blocks/CU
// unit u: c = u>>4 (chunk of 32 rows), i = (u>>1)&7, half = u&1

// ws float slots (every slot written unconditionally every call -> no init
// kernel, no atomics, deterministic under graph replay):
// [0..255] min partials, [256..511] max partials,
// [512..4607] sta partials: slot (c*2+half)*64 + (i*8+j), exclusive per block
#define WS_MINP 0
#define WS_MAXP 256
#define WS_STA  512

__device__ __forceinline__ float qlev(float mn, float step, float mx, int i) {
    return (i == L - 1) ? mx : mn + step * (float)i;
}
__device__ __forceinline__ float ex16(float x, float q) {
    float d = x - q;
    return __expf(-16.f * d * d);
}

__global__ __launch_bounds__(256) void k_minmax(const float4* __restrict__ x4,
                                                float* __restrict__ ws) {
    const int t = threadIdx.x, b = blockIdx.x;
    float mn = 1e30f, mx = -1e30f;
    #pragma unroll
    for (int i = 0; i < 4; ++i) {
        float4 v = x4[b * 1024 + i * 256 + t];
        mn = fminf(mn, fminf(fminf(v.x, v.y), fminf(v.z, v.w)));
        mx = fmaxf(mx, fmaxf(fmaxf(v.x, v.y), fmaxf(v.z, v.w)));
    }
    #pragma unroll
    for (int m = 1; m < 64; m <<= 1) {
        mn = fminf(mn, __shfl_xor(mn, m, 64));
        mx = fmaxf(mx, __shfl_xor(mx, m, 64));
    }
    __shared__ float smn[4], smx[4];
    if ((t & 63) == 0) { smn[t >> 6] = mn; smx[t >> 6] = mx; }
    __syncthreads();
    if (t == 0) {
        ws[WS_MINP + b] = fminf(fminf(smn[0], smn[1]), fminf(smn[2], smn[3]));
        ws[WS_MAXP + b] = fmaxf(fmaxf(smx[0], smx[1]), fmaxf(smx[2], smx[3]));
    }
}

// i-grouped plane-major: unit (c,i,half) computes l-exps ONCE for level i,
// p-exps once for all 8 j, writes quant plane i (the l-values) plus the 8
// co planes i*8+j for its 16 rows. 1.125 exps/output (was 2) and the quant
// pass is free. 512 blocks = 2/CU, zero tail. XCD swizzle: bid%8 = XCD;
// sbid=(bid&7)*64+(bid>>3) gives each XCD 4 whole chunks of x (one L2 fetch).
__global__ __launch_bounds__(256) void k_main(const float* __restrict__ x,
                                              float* __restrict__ out,
                                              float* __restrict__ ws) {
    const int t = threadIdx.x;
    __shared__ float smn[4], smx[4];
    __shared__ float red[4][8];

    // prologue: reduce the 256 min/max partials (L2-resident)
    float mn = ws[WS_MINP + t], mx = ws[WS_MAXP + t];
    #pragma unroll
    for (int m = 1; m < 64; m <<= 1) {
        mn = fminf(mn, __shfl_xor(mn, m, 64));
        mx = fmaxf(mx, __shfl_xor(mx, m, 64));
    }
    if ((t & 63) == 0) { smn[t >> 6] = mn; smx[t >> 6] = mx; }
    __syncthreads();
    const float mnv = fminf(fminf(smn[0], smn[1]), fminf(smn[2], smn[3]));
    const float mxv = fmaxf(fmaxf(smx[0], smx[1]), fmaxf(smx[2], smx[3]));
    const float step = (mxv - mnv) * (1.0f / 7.0f);
    float qv[L];
    #pragma unroll
    for (int j = 0; j < L; ++j) qv[j] = qlev(mnv, step, mxv, j);

    float* __restrict__ quant = out + OUT0;
    float* __restrict__ co    = out + OUT0 + QUANT_ELEMS;

    const int sbid = (blockIdx.x & 7) * (NUNITS / 8) + (blockIdx.x >> 3);
    const int c = sbid >> 4, i = (sbid >> 1) & 7, half = sbid & 1;
    const int r0 = c * 32 + half * UROWS;
    const float qi = qv[i];

    const int w0 = t * 4;
    const bool ok3 = (w0 + 4 < W);     // lane 255's 4th shifted col is the pad

    // software pipeline: cur = row h, (nxt,e) = row h+1 (right source)
    float4 cur = *(const float4*)(x + r0 * W + w0);
    float4 nxt = make_float4(0.f, 0.f, 0.f, 0.f);
    float e = 0.f;
    if (r0 + 1 < H) {
        nxt = *(const float4*)(x + (r0 + 1) * W + w0);
        if (ok3) e = x[(r0 + 1) * W + w0 + 4];
    }

    float acc[L] = {0.f, 0.f, 0.f, 0.f, 0.f, 0.f, 0.f, 0.f};

    for (int r = 0; r < UROWS; ++r) {
        const int h = r0 + r;
        // prefetch row h+2 (next iteration's right row)
        float4 nx2 = make_float4(0.f, 0.f, 0.f, 0.f);
        float e2 = 0.f;
        if (h + 2 < H) {
            nx2 = *(const float4*)(x + (h + 2) * W + w0);
            if (ok3) e2 = x[(h + 2) * W + w0 + 4];
        }

        // l-exps for level i — these ARE quant[i] row h
        float l0 = ex16(cur.x, qi), l1 = ex16(cur.y, qi),
              l2 = ex16(cur.z, qi), l3 = ex16(cur.w, qi);
        float* qp = quant + (i * QH + h) * QW + w0;
        *(float4*)qp = make_float4(l0, l1, l2, l3);
        if (t == 255) qp[4] = 0.0f;     // right pad col (w == 1024)

        float* cb = co + (i * L) * (H * W) + h * W + w0;
        if (h + 1 < H) {
            #pragma unroll
            for (int j = 0; j < L; ++j) {
                const float q = qv[j];
                float p0 = ex16(nxt.y, q);
                float p1 = ex16(nxt.z, q);
                float p2 = ex16(nxt.w, q);
                float p3 = ok3 ? ex16(e, q) : 0.f;
                float v0 = l0 * p0, v1 = l1 * p1, v2 = l2 * p2, v3 = l3 * p3;
                *(float4*)(cb + j * (H * W)) = make_float4(v0, v1, v2, v3);
                acc[j] += (v0 + v1) + (v2 + v3);
            }
        } else {  // h == 1023: shifted row is the zero pad -> co row is zero
            #pragma unroll
            for (int j = 0; j < L; ++j)
                *(float4*)(cb + j * (H * W)) = make_float4(0.f, 0.f, 0.f, 0.f);
        }

        cur = nxt; nxt = nx2; e = e2;
    }

    // bottom pad row of quant plane i (h == 1024), owned by (c==31, half==1)
    if (c == NUNITS / 16 - 1 && half == 1) {
        for (int w = t; w < QW; w += 256)
            quant[(i * QH + H) * QW + w] = 0.0f;
    }

    // per-j wave reduce -> LDS -> 8 exclusive sta slots
    #pragma unroll
    for (int j = 0; j < L; ++j) {
        float a = acc[j];
        #pragma unroll
        for (int m = 1; m < 64; m <<= 1) a += __shfl_xor(a, m, 64);
        if ((t & 63) == 0) red[t >> 6][j] = a;
    }
    __syncthreads();
    if (t < L) {
        float s = (red[0][t] + red[1][t]) + (red[2][t] + red[3][t]);
        ws[WS_STA + (c * 2 + half) * 64 + i * 8 + t] = s;
    }
}

__global__ void k_final(float* __restrict__ out, const float* __restrict__ ws) {
    const int t = threadIdx.x;  // 64 threads
    float mn = 1e30f, mx = -1e30f;
    #pragma unroll
    for (int i = 0; i < 4; ++i) {
        mn = fminf(mn, ws[WS_MINP + i * 64 + t]);
        mx = fmaxf(mx, ws[WS_MAXP + i * 64 + t]);
    }
    #pragma unroll
    for (int m = 1; m < 64; m <<= 1) {
        mn = fminf(mn, __shfl_xor(mn, m, 64));
        mx = fmaxf(mx, __shfl_xor(mx, m, 64));
    }
    const float step = (mx - mn) * (1.0f / 7.0f);

    float s = 0.f;
    #pragma unroll 8
    for (int u = 0; u < 64; ++u) s += ws[WS_STA + u * 64 + t];
    float tot = s;
    #pragma unroll
    for (int m = 1; m < 64; m <<= 1) tot += __shfl_xor(tot, m, 64);

    out[t]       = qlev(mn, step, mx, t & 7);   // q_h[i][j] = q_levels[j]
    out[64 + t]  = qlev(mn, step, mx, t >> 3);  // q_w[i][j] = q_levels[i]
    out[128 + t] = s / tot;                     // normalized sta
}

extern "C" void kernel_launch(void* const* d_in, const int* in_sizes, int n_in,
                              void* d_out, int out_size, void* d_ws, size_t ws_size,
                              hipStream_t stream) {
    const float* x = (const float*)d_in[0];
    float* out = (float*)d_out;
    float* ws = (float*)d_ws;

    k_minmax<<<dim3(256), dim3(256), 0, stream>>>((const float4*)x, ws);
    k_main<<<dim3(NUNITS), dim3(256), 0, stream>>>(x, out, ws);
    k_final<<<dim3(1), dim3(64), 0, stream>>>(out, ws);
}